// Round 7
// baseline (1078.113 us; speedup 1.0000x reference)
//
#include <hip/hip_runtime.h>
#include <hip/hip_bf16.h>

#define N_NODES 100000
#define N_EDGES 3200000
#define IN_DIM 128
#define HIDDEN 64
#define N_GRAPHS 512

#define NT 5                 // source tiles
#define TILE_W 20000         // nodes per source tile (footprint 20000*128B = 2.56 MB < 4 MiB L2)
#define N_KEYS (N_NODES * NT)            // 500000
#define SCAN_BLKS ((N_KEYS + 1023) / 1024)  // 489 (<=512 for scan2)

typedef __hip_bfloat16 bf16;
__device__ __forceinline__ float b2f(bf16 v) { return __bfloat162float(v); }
__device__ __forceinline__ int tile_of(int s) { return (int)((unsigned)s / TILE_W); }

// ---------------- tile-split CSR build: key = dst*NT + tile(src) ----------------
__global__ void deg_count_kernel(const int* __restrict__ src, const int* __restrict__ dst,
                                 int* __restrict__ deg) {
    int e = blockIdx.x * blockDim.x + threadIdx.x;
    if (e < N_EDGES) atomicAdd(&deg[dst[e] * NT + tile_of(src[e])], 1);
}

// block = 256 thr x 4 elems = 1024 keys
__global__ __launch_bounds__(256) void scan1_kernel(const int* __restrict__ cnt,
                                                    int* __restrict__ partials) {
    __shared__ int sd[256];
    int t = threadIdx.x;
    int i0 = blockIdx.x * 1024 + t * 4;
    int s = 0;
    #pragma unroll
    for (int j = 0; j < 4; ++j) {
        int i = i0 + j;
        if (i < N_KEYS) s += cnt[i];
    }
    sd[t] = s;
    __syncthreads();
    for (int k = 128; k > 0; k >>= 1) {
        if (t < k) sd[t] += sd[t + k];
        __syncthreads();
    }
    if (t == 0) partials[blockIdx.x] = sd[0];
}

__global__ __launch_bounds__(512) void scan2_kernel(int* __restrict__ partials) {
    __shared__ int sd[512];
    int t = threadIdx.x;
    int v = (t < SCAN_BLKS) ? partials[t] : 0;
    sd[t] = v;
    __syncthreads();
    for (int off = 1; off < 512; off <<= 1) {
        int u = (t >= off) ? sd[t - off] : 0;
        __syncthreads();
        sd[t] += u;
        __syncthreads();
    }
    partials[t] = sd[t] - v;   // exclusive prefix
}

__global__ __launch_bounds__(256) void scan3_kernel(const int* __restrict__ cnt,
                                                    const int* __restrict__ partials,
                                                    int* __restrict__ base) {
    __shared__ int sd[256];
    int t = threadIdx.x;
    int i0 = blockIdx.x * 1024 + t * 4;
    int v[4], e[4];
    int s = 0;
    #pragma unroll
    for (int j = 0; j < 4; ++j) {
        int i = i0 + j;
        v[j] = (i < N_KEYS) ? cnt[i] : 0;
        e[j] = s;
        s += v[j];
    }
    sd[t] = s;
    __syncthreads();
    int mine = s;
    for (int off = 1; off < 256; off <<= 1) {
        int u = (t >= off) ? sd[t - off] : 0;
        __syncthreads();
        sd[t] += u;
        __syncthreads();
    }
    int excl = sd[t] - mine + partials[blockIdx.x];
    #pragma unroll
    for (int j = 0; j < 4; ++j) {
        int i = i0 + j;
        if (i < N_KEYS) base[i] = excl + e[j];
    }
    if (blockIdx.x == 0 && t == 0) base[N_KEYS] = N_EDGES;
}

__global__ void dis_kernel(const int* __restrict__ base, float* __restrict__ dis) {
    int i = blockIdx.x * blockDim.x + threadIdx.x;
    if (i < N_NODES) {
        int deg = base[(i + 1) * NT] - base[i * NT];   // in-degree over all tiles
        dis[i] = rsqrtf((float)(deg + 1));             // +1 self-loop
    }
}

__global__ void fill_kernel(const int* __restrict__ src, const int* __restrict__ dst,
                            const int* __restrict__ base, int* __restrict__ fcnt,
                            int* __restrict__ csr) {
    int e = blockIdx.x * blockDim.x + threadIdx.x;
    if (e < N_EDGES) {
        int key = dst[e] * NT + tile_of(src[e]);
        int pos = base[key] + atomicAdd(&fcnt[key], 1);
        csr[pos] = src[e];
    }
}

// ---------------- GEMM: hd[node] = bf16((in[node] @ W) * dis[node]) ----------
template <int K>
__global__ __launch_bounds__(256) void gemm_kernel(
        const float* __restrict__ in, const float* __restrict__ W,
        const float* __restrict__ dis, bf16* __restrict__ hd) {
    int tid = threadIdx.x;
    int lane = tid & 63;
    float Wr[K];
    #pragma unroll
    for (int k = 0; k < K; ++k) Wr[k] = W[k * HIDDEN + lane];   // coalesced
    int w = __builtin_amdgcn_readfirstlane(tid >> 6);           // provably uniform
    int wave = blockIdx.x * 4 + w;
    int nw = gridDim.x * 4;
    for (int n0 = wave * 4; n0 < N_NODES; n0 += nw * 4) {
        const float* xr = in + (size_t)n0 * K;
        float a0 = 0.f, a1 = 0.f, a2 = 0.f, a3 = 0.f;
        #pragma unroll
        for (int k = 0; k < K; ++k) {
            float wv = Wr[k];
            a0 = fmaf(xr[k],         wv, a0);
            a1 = fmaf(xr[K + k],     wv, a1);
            a2 = fmaf(xr[2 * K + k], wv, a2);
            a3 = fmaf(xr[3 * K + k], wv, a3);
        }
        bf16* o = hd + (size_t)n0 * HIDDEN + lane;
        o[0]          = __float2bfloat16(a0 * dis[n0]);
        o[HIDDEN]     = __float2bfloat16(a1 * dis[n0 + 1]);
        o[2 * HIDDEN] = __float2bfloat16(a2 * dis[n0 + 2]);
        o[3 * HIDDEN] = __float2bfloat16(a3 * dis[n0 + 3]);
    }
}

// ---------------- tiled pull ----------------
// Tile t gathers only src in [t*TILE_W,(t+1)*TILE_W) -> 2.56 MB L2-resident.
// buf = f32 partial-sum accumulator; tile NT-1 finalizes in place (POOL=0: act)
// or does mean-pool atomics (POOL=1). Self-loop added by the tile owning node.
template <int POOL>
__global__ __launch_bounds__(256) void pull_kernel(
        const bf16* __restrict__ hd, const float* __restrict__ dis,
        const int* __restrict__ base, const int* __restrict__ csr,
        const float* __restrict__ bias,
        float* __restrict__ buf,
        const int* __restrict__ batch, float* __restrict__ pool,
        float* __restrict__ cnt, int tile) {
    int w = threadIdx.x >> 6, lane = threadIdx.x & 63;
    int node = blockIdx.x * 4 + w;
    if (node >= N_NODES) return;   // wave-uniform exit
    int kbase = node * NT + tile;
    int beg = base[kbase], end = base[kbase + 1];
    float a0 = 0.f, a1 = 0.f, a2 = 0.f, a3 = 0.f;
    for (int j = beg; j < end; j += 64) {
        int rem = end - j;
        int m = rem < 64 ? rem : 64;
        int idx = (lane < m) ? csr[j + lane] : 0;
        int t2 = 0;
        for (; t2 + 4 <= m; t2 += 4) {
            int s0 = __shfl(idx, t2);
            int s1 = __shfl(idx, t2 + 1);
            int s2 = __shfl(idx, t2 + 2);
            int s3 = __shfl(idx, t2 + 3);
            a0 += b2f(hd[(size_t)s0 * HIDDEN + lane]);
            a1 += b2f(hd[(size_t)s1 * HIDDEN + lane]);
            a2 += b2f(hd[(size_t)s2 * HIDDEN + lane]);
            a3 += b2f(hd[(size_t)s3 * HIDDEN + lane]);
        }
        for (; t2 < m; ++t2) {
            int s = __shfl(idx, t2);
            a0 += b2f(hd[(size_t)s * HIDDEN + lane]);
        }
    }
    float A = (a0 + a1) + (a2 + a3);
    if (tile == tile_of(node))                       // wave-uniform branch
        A += b2f(hd[(size_t)node * HIDDEN + lane]);  // self-loop (in-footprint)
    float* accp = buf + (size_t)node * HIDDEN + lane;
    if (tile > 0) A += *accp;
    if (tile < NT - 1) {
        *accp = A;
    } else {
        float row = fmaf(dis[node], A, bias[lane]);
        float v = row > 0.f ? row : 0.f;
        if (POOL == 0) {
            *accp = v;                               // finalize act in place
        } else {
            int g = batch[node];
            atomicAdd(&pool[g * HIDDEN + lane], v);
            if (lane == 0) atomicAdd(&cnt[g], 1.0f);
        }
    }
}

__global__ void final_kernel(const float* __restrict__ pool,
                             const float* __restrict__ cnt,
                             float* __restrict__ out) {
    int i = blockIdx.x * blockDim.x + threadIdx.x;
    if (i < N_GRAPHS * HIDDEN) {
        float c = cnt[i >> 6];
        c = c > 1.0f ? c : 1.0f;
        out[i] = pool[i] / c;
    }
}

extern "C" void kernel_launch(void* const* d_in, const int* in_sizes, int n_in,
                              void* d_out, int out_size, void* d_ws, size_t ws_size,
                              hipStream_t stream) {
    const float* x  = (const float*)d_in[0];
    const float* W1 = (const float*)d_in[1];
    const float* b1 = (const float*)d_in[2];
    const float* W2 = (const float*)d_in[3];
    const float* b2 = (const float*)d_in[4];
    const int* edge_index = (const int*)d_in[5];
    const int* batch      = (const int*)d_in[6];
    float* out = (float*)d_out;
    (void)in_sizes; (void)n_in; (void)out_size; (void)ws_size;

    char* ws = (char*)d_ws;
    int*   deg_cnt  = (int*)  (ws + 0);          // 2,000,000
    int*   fcnt     = (int*)  (ws + 2000000);    // 2,000,000
    float* pool     = (float*)(ws + 4000000);    // 131,072
    float* cnt      = (float*)(ws + 4131072);    // 2,048   (zero region ends 4,133,120)
    int*   partials = (int*)  (ws + 4133120);    // 2,048
    float* dis      = (float*)(ws + 4135168);    // 400,000
    int*   base     = (int*)  (ws + 4535168);    // 2,000,032 (N_KEYS+1 ints, padded)
    int*   csr      = (int*)  (ws + 6535200);    // 12,800,000
    bf16*  hd       = (bf16*) (ws + 19335200);   // 12,800,000
    float* buf      = (float*)(ws + 32135200);   // 25,600,000 (acc + act, merged) -> ends 57,735,200

    const int* srcv = edge_index;            // edge_index[0]
    const int* dstv = edge_index + N_EDGES;  // edge_index[1]

    // zero: deg_cnt, fcnt, pool, cnt (contiguous region)
    hipMemsetAsync(ws, 0, 4133120, stream);

    // tile-split CSR build (reused by both layers)
    deg_count_kernel<<<(N_EDGES + 255) / 256, 256, 0, stream>>>(srcv, dstv, deg_cnt);
    scan1_kernel<<<SCAN_BLKS, 256, 0, stream>>>(deg_cnt, partials);
    scan2_kernel<<<1, 512, 0, stream>>>(partials);
    scan3_kernel<<<SCAN_BLKS, 256, 0, stream>>>(deg_cnt, partials, base);
    dis_kernel<<<(N_NODES + 255) / 256, 256, 0, stream>>>(base, dis);
    fill_kernel<<<(N_EDGES + 255) / 256, 256, 0, stream>>>(srcv, dstv, base, fcnt, csr);

    // layer 1: hd = bf16((x@W1)*dis) ; buf <- relu(dis*(tiled gather+self) + b1)
    gemm_kernel<IN_DIM><<<1024, 256, 0, stream>>>(x, W1, dis, hd);
    for (int t = 0; t < NT; ++t)
        pull_kernel<0><<<(N_NODES + 3) / 4, 256, 0, stream>>>(
            hd, dis, base, csr, b1, buf, nullptr, nullptr, nullptr, t);

    // layer 2: hd = bf16((buf@W2)*dis) ; tiled gather + fused relu+b2+mean-pool
    gemm_kernel<HIDDEN><<<1024, 256, 0, stream>>>(buf, W2, dis, hd);
    for (int t = 0; t < NT; ++t)
        pull_kernel<1><<<(N_NODES + 3) / 4, 256, 0, stream>>>(
            hd, dis, base, csr, b2, buf, batch, pool, cnt, t);

    final_kernel<<<(N_GRAPHS * HIDDEN + 255) / 256, 256, 0, stream>>>(pool, cnt, out);
}

// Round 8
// 951.909 us; speedup vs baseline: 1.1326x; 1.1326x over previous
//
#include <hip/hip_runtime.h>
#include <hip/hip_bf16.h>

#define N_NODES 100000
#define N_EDGES 3200000
#define IN_DIM 128
#define HIDDEN 64
#define N_GRAPHS 512
#define SCAN_BLOCKS 391   // ceil(N_NODES/256)
#define EPW 256           // edges per wave strip (N_EDGES % EPW == 0)
#define PULL_BLOCKS (N_EDGES / EPW / 4)   // 3125

typedef __hip_bfloat16 bf16;
__device__ __forceinline__ float b2f(bf16 v) { return __bfloat162float(v); }

// ---------------- CSR build ----------------
__global__ void deg_count_kernel(const int* __restrict__ dst, int* __restrict__ deg) {
    int e = blockIdx.x * blockDim.x + threadIdx.x;
    if (e < N_EDGES) atomicAdd(&deg[dst[e]], 1);
}

__global__ __launch_bounds__(256) void scan1_kernel(const int* __restrict__ cnt,
                                                    int* __restrict__ partials) {
    __shared__ int sd[256];
    int t = threadIdx.x;
    int i = blockIdx.x * 256 + t;
    sd[t] = (i < N_NODES) ? cnt[i] : 0;
    __syncthreads();
    for (int s = 128; s > 0; s >>= 1) {
        if (t < s) sd[t] += sd[t + s];
        __syncthreads();
    }
    if (t == 0) partials[blockIdx.x] = sd[0];
}

__global__ __launch_bounds__(512) void scan2_kernel(int* __restrict__ partials) {
    __shared__ int sd[512];
    int t = threadIdx.x;
    int v = (t < SCAN_BLOCKS) ? partials[t] : 0;
    sd[t] = v;
    __syncthreads();
    for (int off = 1; off < 512; off <<= 1) {
        int u = (t >= off) ? sd[t - off] : 0;
        __syncthreads();
        sd[t] += u;
        __syncthreads();
    }
    partials[t] = sd[t] - v;   // exclusive prefix
}

__global__ __launch_bounds__(256) void scan3_kernel(const int* __restrict__ cnt,
                                                    const int* __restrict__ partials,
                                                    int* __restrict__ base,
                                                    float* __restrict__ dis) {
    __shared__ int sd[256];
    int t = threadIdx.x;
    int i = blockIdx.x * 256 + t;
    int v = (i < N_NODES) ? cnt[i] : 0;
    sd[t] = v;
    __syncthreads();
    for (int off = 1; off < 256; off <<= 1) {
        int u = (t >= off) ? sd[t - off] : 0;
        __syncthreads();
        sd[t] += u;
        __syncthreads();
    }
    if (i < N_NODES) {
        base[i] = partials[blockIdx.x] + sd[t] - v;     // exclusive
        dis[i] = rsqrtf((float)(v + 1));                // +1 self-loop
    }
    if (blockIdx.x == 0 && t == 0) base[N_NODES] = N_EDGES;
}

// csr entry = (src, dst) packed; dst-contiguous segments
__global__ void fill_kernel(const int* __restrict__ src, const int* __restrict__ dst,
                            const int* __restrict__ base, int* __restrict__ fcnt,
                            uint2* __restrict__ csr) {
    int e = blockIdx.x * blockDim.x + threadIdx.x;
    if (e < N_EDGES) {
        int d = dst[e];
        int pos = base[d] + atomicAdd(&fcnt[d], 1);
        csr[pos] = make_uint2((unsigned)src[e], (unsigned)d);
    }
}

// ---------------- GEMM: hd[node] = bf16((in[node] @ W) * dis[node]) ----------
template <int K>
__global__ __launch_bounds__(256) void gemm_kernel(
        const float* __restrict__ in, const float* __restrict__ W,
        const float* __restrict__ dis, bf16* __restrict__ hd) {
    int tid = threadIdx.x;
    int lane = tid & 63;
    float Wr[K];
    #pragma unroll
    for (int k = 0; k < K; ++k) Wr[k] = W[k * HIDDEN + lane];   // coalesced
    int w = __builtin_amdgcn_readfirstlane(tid >> 6);           // provably uniform
    int wave = blockIdx.x * 4 + w;
    int nw = gridDim.x * 4;
    for (int n0 = wave * 4; n0 < N_NODES; n0 += nw * 4) {
        const float* xr = in + (size_t)n0 * K;
        float a0 = 0.f, a1 = 0.f, a2 = 0.f, a3 = 0.f;
        #pragma unroll
        for (int k = 0; k < K; ++k) {
            float wv = Wr[k];
            a0 = fmaf(xr[k],         wv, a0);
            a1 = fmaf(xr[K + k],     wv, a1);
            a2 = fmaf(xr[2 * K + k], wv, a2);
            a3 = fmaf(xr[3 * K + k], wv, a3);
        }
        bf16* o = hd + (size_t)n0 * HIDDEN + lane;
        o[0]          = __float2bfloat16(a0 * dis[n0]);
        o[HIDDEN]     = __float2bfloat16(a1 * dis[n0 + 1]);
        o[2 * HIDDEN] = __float2bfloat16(a2 * dis[n0 + 2]);
        o[3 * HIDDEN] = __float2bfloat16(a3 * dis[n0 + 3]);
    }
}

// ---------------- acc init: acc[i] = f32(hd[i])  (self-loop contribution) ----
__global__ void init_acc_kernel(const unsigned* __restrict__ hdu, float4* __restrict__ acc4) {
    int i = blockIdx.x * blockDim.x + threadIdx.x;
    int n4 = N_NODES * HIDDEN / 4;
    for (; i < n4; i += gridDim.x * blockDim.x) {
        unsigned a = hdu[i * 2], b = hdu[i * 2 + 1];
        float4 r;
        r.x = __uint_as_float(a << 16);
        r.y = __uint_as_float(a & 0xffff0000u);
        r.z = __uint_as_float(b << 16);
        r.w = __uint_as_float(b & 0xffff0000u);
        acc4[i] = r;
    }
}

// ---------------- flat edge-centric pull ----------------
// Wave owns edges [wave*EPW, wave*EPW+EPW). All 4 csr chunks loaded up-front;
// 8-gather ping-pong pipeline; lane=channel running sum; atomic row flush on
// (wave-uniform) dst change. No per-node load chain anywhere.
__global__ __launch_bounds__(256) void pull_kernel(
        const bf16* __restrict__ hd, const uint2* __restrict__ csr,
        float* __restrict__ acc) {
    int w = threadIdx.x >> 6, lane = threadIdx.x & 63;
    int wave = blockIdx.x * 4 + w;
    size_t e0 = (size_t)wave * EPW;
    uint2 c0 = csr[e0 + lane];
    uint2 c1 = csr[e0 + 64 + lane];
    uint2 c2 = csr[e0 + 128 + lane];
    uint2 c3 = csr[e0 + 192 + lane];
    float G0[8], G1[8];
    int cur = -1;
    float A = 0.f;
    // prolog: issue group 0
    #pragma unroll
    for (int i = 0; i < 8; ++i) {
        int s = __shfl((int)c0.x, i);
        G0[i] = b2f(hd[(size_t)s * HIDDEN + lane]);
    }
    #pragma unroll
    for (int g = 0; g < 32; ++g) {
        if (g < 31) {   // issue group g+1 into the other buffer
            #pragma unroll
            for (int i = 0; i < 8; ++i) {
                int t = (g + 1) * 8 + i;
                int ch = t >> 6;
                unsigned sx = ch == 0 ? c0.x : ch == 1 ? c1.x : ch == 2 ? c2.x : c3.x;
                int s = __shfl((int)sx, t & 63);
                float* G = (g & 1) ? G0 : G1;
                G[i] = b2f(hd[(size_t)s * HIDDEN + lane]);
            }
        }
        #pragma unroll
        for (int i = 0; i < 8; ++i) {   // consume group g
            int t = g * 8 + i;
            int ch = t >> 6;
            unsigned dx = ch == 0 ? c0.y : ch == 1 ? c1.y : ch == 2 ? c2.y : c3.y;
            int d = __shfl((int)dx, t & 63);
            float* G = (g & 1) ? G1 : G0;
            if (d != cur) {   // wave-uniform in practice
                if (cur >= 0) atomicAdd(&acc[(size_t)cur * HIDDEN + lane], A);
                A = 0.f;
                cur = d;
            }
            A += G[i];
        }
    }
    if (cur >= 0) atomicAdd(&acc[(size_t)cur * HIDDEN + lane], A);
}

// ---------------- finalize layer 1: acc = relu(dis*acc + b1), in place -------
__global__ void finalize1_kernel(float* __restrict__ acc, const float* __restrict__ dis,
                                 const float* __restrict__ bias) {
    int i = blockIdx.x * blockDim.x + threadIdx.x;   // float4 granularity
    int n4 = N_NODES * HIDDEN / 4;
    if (i < n4) {
        int node = (i * 4) >> 6;
        int ch = (i * 4) & 63;
        float dn = dis[node];
        float4 v = ((float4*)acc)[i];
        float4 bb = *(const float4*)(bias + ch);
        v.x = fmaf(dn, v.x, bb.x); v.y = fmaf(dn, v.y, bb.y);
        v.z = fmaf(dn, v.z, bb.z); v.w = fmaf(dn, v.w, bb.w);
        v.x = v.x > 0.f ? v.x : 0.f;
        v.y = v.y > 0.f ? v.y : 0.f;
        v.z = v.z > 0.f ? v.z : 0.f;
        v.w = v.w > 0.f ? v.w : 0.f;
        ((float4*)acc)[i] = v;
    }
}

// ---------------- finalize layer 2: relu(dis*acc+b2) -> mean-pool atomics ----
__global__ __launch_bounds__(256) void finalize2_kernel(
        const float* __restrict__ acc, const float* __restrict__ dis,
        const float* __restrict__ bias, const int* __restrict__ batch,
        float* __restrict__ pool, float* __restrict__ cnt) {
    int w = threadIdx.x >> 6, lane = threadIdx.x & 63;
    int node = blockIdx.x * 4 + w;
    if (node >= N_NODES) return;
    float v = fmaf(dis[node], acc[(size_t)node * HIDDEN + lane], bias[lane]);
    v = v > 0.f ? v : 0.f;
    int g = batch[node];
    atomicAdd(&pool[g * HIDDEN + lane], v);
    if (lane == 0) atomicAdd(&cnt[g], 1.0f);
}

__global__ void final_kernel(const float* __restrict__ pool,
                             const float* __restrict__ cnt,
                             float* __restrict__ out) {
    int i = blockIdx.x * blockDim.x + threadIdx.x;
    if (i < N_GRAPHS * HIDDEN) {
        float c = cnt[i >> 6];
        c = c > 1.0f ? c : 1.0f;
        out[i] = pool[i] / c;
    }
}

extern "C" void kernel_launch(void* const* d_in, const int* in_sizes, int n_in,
                              void* d_out, int out_size, void* d_ws, size_t ws_size,
                              hipStream_t stream) {
    const float* x  = (const float*)d_in[0];
    const float* W1 = (const float*)d_in[1];
    const float* b1 = (const float*)d_in[2];
    const float* W2 = (const float*)d_in[3];
    const float* b2 = (const float*)d_in[4];
    const int* edge_index = (const int*)d_in[5];
    const int* batch      = (const int*)d_in[6];
    float* out = (float*)d_out;
    (void)in_sizes; (void)n_in; (void)out_size; (void)ws_size;

    char* ws = (char*)d_ws;
    int*   deg_cnt  = (int*)  (ws + 0);         // 400000
    int*   fcnt     = (int*)  (ws + 400000);    // 400000
    float* pool     = (float*)(ws + 800000);    // 131072
    float* cnt      = (float*)(ws + 931072);    // 2048   (zero region ends 933120)
    int*   partials = (int*)  (ws + 933120);    // 2048
    float* dis      = (float*)(ws + 935168);    // 400000
    int*   base     = (int*)  (ws + 1335168);   // 400032 (padded)
    uint2* csr      = (uint2*)(ws + 1735200);   // 25600000
    bf16*  hd       = (bf16*) (ws + 27335200);  // 12800000
    float* acc      = (float*)(ws + 40135200);  // 25600000 -> ends 65735200

    const int* srcv = edge_index;            // edge_index[0]
    const int* dstv = edge_index + N_EDGES;  // edge_index[1]

    // zero: deg_cnt, fcnt, pool, cnt (contiguous region)
    hipMemsetAsync(ws, 0, 933120, stream);

    // CSR build (packed (src,dst); reused by both layers)
    deg_count_kernel<<<(N_EDGES + 255) / 256, 256, 0, stream>>>(dstv, deg_cnt);
    scan1_kernel<<<SCAN_BLOCKS, 256, 0, stream>>>(deg_cnt, partials);
    scan2_kernel<<<1, 512, 0, stream>>>(partials);
    scan3_kernel<<<SCAN_BLOCKS, 256, 0, stream>>>(deg_cnt, partials, base, dis);
    fill_kernel<<<(N_EDGES + 255) / 256, 256, 0, stream>>>(srcv, dstv, base, fcnt, csr);

    // layer 1
    gemm_kernel<IN_DIM><<<1024, 256, 0, stream>>>(x, W1, dis, hd);
    init_acc_kernel<<<1024, 256, 0, stream>>>((const unsigned*)hd, (float4*)acc);
    pull_kernel<<<PULL_BLOCKS, 256, 0, stream>>>(hd, csr, acc);
    finalize1_kernel<<<(N_NODES * HIDDEN / 4 + 255) / 256, 256, 0, stream>>>(acc, dis, b1);

    // layer 2 (acc now holds act; consumed by gemm, then re-initialized)
    gemm_kernel<HIDDEN><<<1024, 256, 0, stream>>>(acc, W2, dis, hd);
    init_acc_kernel<<<1024, 256, 0, stream>>>((const unsigned*)hd, (float4*)acc);
    pull_kernel<<<PULL_BLOCKS, 256, 0, stream>>>(hd, csr, acc);
    finalize2_kernel<<<(N_NODES + 3) / 4, 256, 0, stream>>>(acc, dis, b2, batch, pool, cnt);

    final_kernel<<<(N_GRAPHS * HIDDEN + 255) / 256, 256, 0, stream>>>(pool, cnt, out);
}